// Round 1
// baseline (20929.494 us; speedup 1.0000x reference)
//
#include <hip/hip_runtime.h>

// LSTM LM forward on gfx950.
// Design:
//  - Output head folded: Y = H·v + c0, v = W_hq@dense_w (exact reassociation).
//  - Recurrent GEMM D = W^T · A^T with A=[H|x] (K=640), MFMA 16x16x32 bf16,
//    weights persistent in VGPRs (80/lane), fp32 state/gates.
//  - 32 cooperative WGs x 256thr; wave q owns h in [4q,4q+4); per-lane acc regs
//    {i,f,o,c} for one (b,h) -> no cross-lane in the cell update.
//  - H double-buffered bf16 in ws; one device barrier per step (sense counter +
//    __threadfence for cross-XCD visibility).

typedef short bf16x8 __attribute__((ext_vector_type(8)));
typedef float f32x4  __attribute__((ext_vector_type(4)));
typedef unsigned short ushort_t;

#define S_LEN 1024
#define NB    64
#define NH    512
#define NE    128
#define NWG   32

// workspace byte offsets
#define OFF_WPACK 0UL                         // 128*20*64*16 = 2,621,440 B
#define OFF_XBF   2621440UL                   // 1024*64*128*2 = 16,777,216 B
#define OFF_HBUF  (2621440UL + 16777216UL)    // 2*64*512*2 = 131,072 B
#define OFF_V     (OFF_HBUF + 131072UL)       // 512*4 B
#define OFF_C0S   (OFF_V + 2048UL)            // 4 B
#define OFF_BAR   (OFF_C0S + 16UL)            // 8 B

__device__ __forceinline__ ushort_t f2bf(float f){
    union { float f; unsigned u; } v; v.f = f;
    unsigned u = v.u;
    unsigned r = (u + 0x7fffu + ((u >> 16) & 1u)) >> 16;
    return (ushort_t)r;
}
__device__ __forceinline__ float sigm(float x){ return 1.f / (1.f + __expf(-x)); }
__device__ __forceinline__ float tanh_(float x){ float e = __expf(2.f * x); return (e - 1.f) / (e + 1.f); }

// ---- prep: pack W into MFMA A-operand fragments (bf16) ----------------------
// wpack[q][ks][lane][j]: A[m=lane&15][k=32*ks + (lane>>4)*8 + j]
//   m -> h = 4q + (m>>2), gate g = m&3 (g: 0=i,1=f,2=o,3=c)
//   k<512: W_h[g][k][h];  k>=512: W_x[g][k-512][h]
__global__ void pack_weights(const float* __restrict__ Wxi, const float* __restrict__ Whi,
                             const float* __restrict__ Wxf, const float* __restrict__ Whf,
                             const float* __restrict__ Wxo, const float* __restrict__ Who,
                             const float* __restrict__ Wxc, const float* __restrict__ Whc,
                             ushort_t* __restrict__ wpack){
    int bid = blockIdx.x;            // = q*20 + ks
    int q = bid / 20, ks = bid % 20;
    int l = threadIdx.x;             // 0..63
    int m = l & 15, quad = l >> 4;
    int h = q * 4 + (m >> 2), g = m & 3;
    const float* Wh = (g == 0) ? Whi : (g == 1) ? Whf : (g == 2) ? Who : Whc;
    const float* Wx = (g == 0) ? Wxi : (g == 1) ? Wxf : (g == 2) ? Wxo : Wxc;
    union { ushort_t u[8]; uint4 v4; } tmp;
    #pragma unroll
    for (int j = 0; j < 8; j++){
        int k = ks * 32 + quad * 8 + j;
        float w = (k < NH) ? Wh[(size_t)k * NH + h] : Wx[(size_t)(k - NH) * NH + h];
        tmp.u[j] = f2bf(w);
    }
    *(uint4*)(wpack + ((size_t)bid * 64 + l) * 8) = tmp.v4;
}

// ---- prep: bf16 embeddings, layout [s][b][e] --------------------------------
__global__ void prep_x(const int* __restrict__ inputs, const float* __restrict__ emb,
                       ushort_t* __restrict__ xbf){
    unsigned tid = blockIdx.x * 256u + threadIdx.x;   // = (s*64+b)*128 + e
    unsigned e = tid & 127u;
    unsigned b = (tid >> 7) & 63u;
    unsigned s = tid >> 13;
    int row = inputs[(size_t)b * S_LEN + s];
    xbf[tid] = f2bf(emb[(size_t)row * NE + e]);
}

// ---- prep: v = W_hq @ dense_w, c0, barrier init, Hbuf[0]=bf16(H0) -----------
__global__ void prep_v(const float* __restrict__ Whq, const float* __restrict__ bq,
                       const float* __restrict__ dw, const float* __restrict__ db,
                       const float* __restrict__ H0, float* __restrict__ v,
                       float* __restrict__ c0, unsigned* __restrict__ bar,
                       ushort_t* __restrict__ hbuf){
    int h = threadIdx.x;   // 512 threads, 1 block
    float a = 0.f;
    for (int e = 0; e < NE; e++) a += Whq[(size_t)h * NE + e] * dw[e];
    v[h] = a;
    if (h == 0){
        float c = db[0];
        for (int e = 0; e < NE; e++) c += bq[e] * dw[e];
        *c0 = c;
        bar[0] = 0u; bar[1] = 0u;
    }
    for (int b = 0; b < NB; b++) hbuf[(size_t)b * NH + h] = f2bf(H0[(size_t)b * NH + h]);
}

// ---- prep: init Y region of d_out to c0 (atomics accumulate onto it) --------
__global__ void init_y(const float* __restrict__ c0, float* __restrict__ dout){
    int tid = blockIdx.x * 256 + threadIdx.x;   // 65536 = S*B
    dout[tid] = *c0;
}

// ---- the recurrence ---------------------------------------------------------
__launch_bounds__(256, 1)
__global__ void lstm_coop(const float* __restrict__ C0,
                          const float* __restrict__ b_i, const float* __restrict__ b_f,
                          const float* __restrict__ b_o, const float* __restrict__ b_c,
                          const ushort_t* __restrict__ wpack, const ushort_t* __restrict__ xbf,
                          ushort_t* __restrict__ hbuf, const float* __restrict__ v,
                          unsigned* __restrict__ bar, float* __restrict__ dout){
    __shared__ float yred[4][NB];
    const int tid  = threadIdx.x;
    const int lane = tid & 63;
    const int wv   = tid >> 6;
    const int q    = blockIdx.x * 4 + wv;   // global wave id, 0..127
    const int quad = lane >> 4;
    const int col  = lane & 15;
    const int h    = q * 4 + quad;          // this lane's h column

    // persistent weights: 20 A-fragments (K=640)
    bf16x8 wfrag[20];
    #pragma unroll
    for (int ks = 0; ks < 20; ks++)
        wfrag[ks] = *(const bf16x8*)(wpack + ((size_t)(q * 20 + ks) * 64 + lane) * 8);

    const float bias0 = b_i[h], bias1 = b_f[h], bias2 = b_o[h], bias3 = b_c[h];
    const float vv = v[h];

    float C[4];
    #pragma unroll
    for (int t = 0; t < 4; t++) C[t] = C0[(size_t)(t * 16 + col) * NH + h];

    for (int s = 0; s < S_LEN; s++){
        const ushort_t* hrd = hbuf + (size_t)(s & 1) * NB * NH;
        ushort_t*       hwr = hbuf + (size_t)((s + 1) & 1) * NB * NH;
        const ushort_t* xrd = xbf + (size_t)s * NB * NE;

        f32x4 acc[4];
        #pragma unroll
        for (int t = 0; t < 4; t++) acc[t] = (f32x4){0.f, 0.f, 0.f, 0.f};

        // K = 0..511 : H part (B-frag: lane holds H[b=16t+col][k .. k+7])
        #pragma unroll
        for (int ks = 0; ks < 16; ks++){
            #pragma unroll
            for (int t = 0; t < 4; t++){
                bf16x8 bfr = *(const bf16x8*)(hrd + (size_t)(t * 16 + col) * NH + ks * 32 + quad * 8);
                acc[t] = __builtin_amdgcn_mfma_f32_16x16x32_bf16(wfrag[ks], bfr, acc[t], 0, 0, 0);
            }
        }
        // K = 512..639 : x part
        #pragma unroll
        for (int ks = 16; ks < 20; ks++){
            #pragma unroll
            for (int t = 0; t < 4; t++){
                bf16x8 bfr = *(const bf16x8*)(xrd + (size_t)(t * 16 + col) * NE + (ks - 16) * 32 + quad * 8);
                acc[t] = __builtin_amdgcn_mfma_f32_16x16x32_bf16(wfrag[ks], bfr, acc[t], 0, 0, 0);
            }
        }

        // cell update: acc[t] regs = {i,f,o,c} gates for batch 16t+col at column h
        #pragma unroll
        for (int t = 0; t < 4; t++){
            const int b = t * 16 + col;
            float I = sigm(acc[t][0] + bias0);
            float F = sigm(acc[t][1] + bias1);
            float O = sigm(acc[t][2] + bias2);
            float G = tanh_(acc[t][3] + bias3);
            float Cn = F * C[t] + I * G;
            float Hn = O * tanh_(Cn);
            C[t] = Cn;
            hwr[(size_t)b * NH + h] = f2bf(Hn);
            float p = Hn * vv;                      // Y partial for (b): sum over this wave's 4 h
            p += __shfl_xor(p, 16, 64);
            p += __shfl_xor(p, 32, 64);
            if (quad == 0) yred[wv][b] = p;
            if (s == S_LEN - 1){
                dout[65536 + (size_t)b * NH + h] = Hn;   // final H
                dout[98304 + (size_t)b * NH + h] = Cn;   // final C
            }
        }
        __syncthreads();
        if (tid < NB){
            float yy = yred[0][tid] + yred[1][tid] + yred[2][tid] + yred[3][tid];
            atomicAdd(&dout[(size_t)s * NB + tid], yy);
        }
        if (s == S_LEN - 1) break;

        // device-wide barrier (release H writes, acquire for next step's reads)
        __syncthreads();
        if (tid == 0){
            __threadfence();
            unsigned prev = atomicAdd(&bar[0], 1u);
            if (prev == NWG - 1){
                atomicExch(&bar[0], 0u);
                __threadfence();
                atomicAdd(&bar[1], 1u);
            } else {
                while (atomicAdd(&bar[1], 0u) < (unsigned)(s + 1)) __builtin_amdgcn_s_sleep(1);
            }
            __threadfence();
        }
        __syncthreads();
    }
}

extern "C" void kernel_launch(void* const* d_in, const int* in_sizes, int n_in,
                              void* d_out, int out_size, void* d_ws, size_t ws_size,
                              hipStream_t stream){
    const int*   inputs = (const int*)  d_in[0];
    const float* H0     = (const float*)d_in[1];
    const float* C0     = (const float*)d_in[2];
    const float* emb    = (const float*)d_in[3];
    const float* W_xi   = (const float*)d_in[4];
    const float* W_hi   = (const float*)d_in[5];
    const float* b_i    = (const float*)d_in[6];
    const float* W_xf   = (const float*)d_in[7];
    const float* W_hf   = (const float*)d_in[8];
    const float* b_f    = (const float*)d_in[9];
    const float* W_xo   = (const float*)d_in[10];
    const float* W_ho   = (const float*)d_in[11];
    const float* b_o    = (const float*)d_in[12];
    const float* W_xc   = (const float*)d_in[13];
    const float* W_hc   = (const float*)d_in[14];
    const float* b_c    = (const float*)d_in[15];
    const float* W_hq   = (const float*)d_in[16];
    const float* b_q    = (const float*)d_in[17];
    const float* dw     = (const float*)d_in[18];
    const float* db     = (const float*)d_in[19];
    float* dout = (float*)d_out;

    char* ws = (char*)d_ws;
    ushort_t* wpack = (ushort_t*)(ws + OFF_WPACK);
    ushort_t* xbf   = (ushort_t*)(ws + OFF_XBF);
    ushort_t* hbuf  = (ushort_t*)(ws + OFF_HBUF);
    float*    v     = (float*)   (ws + OFF_V);
    float*    c0    = (float*)   (ws + OFF_C0S);
    unsigned* bar   = (unsigned*)(ws + OFF_BAR);

    pack_weights<<<dim3(128 * 20), dim3(64), 0, stream>>>(W_xi, W_hi, W_xf, W_hf,
                                                          W_xo, W_ho, W_xc, W_hc, wpack);
    prep_x<<<dim3((S_LEN * NB * NE) / 256), dim3(256), 0, stream>>>(inputs, emb, xbf);
    prep_v<<<dim3(1), dim3(512), 0, stream>>>(W_hq, b_q, dw, db, H0, v, c0, bar, hbuf);
    init_y<<<dim3((S_LEN * NB) / 256), dim3(256), 0, stream>>>(c0, dout);

    void* args[] = { (void*)&C0, (void*)&b_i, (void*)&b_f, (void*)&b_o, (void*)&b_c,
                     (void*)&wpack, (void*)&xbf, (void*)&hbuf, (void*)&v,
                     (void*)&bar, (void*)&dout };
    hipLaunchCooperativeKernel((void*)lstm_coop, dim3(NWG), dim3(256), args, 0, stream);
}

// Round 2
// 20098.090 us; speedup vs baseline: 1.0414x; 1.0414x over previous
//
#include <hip/hip_runtime.h>

// LSTM LM forward on gfx950.
// Design:
//  - Output head folded: Y = H·v + c0, v = W_hq@dense_w (exact reassociation).
//  - Recurrent GEMM D = W^T · A^T with A=[H|x] (K=640), MFMA 16x16x32 bf16,
//    weights persistent in VGPRs (80/lane), fp32 state/gates.
//  - 32 cooperative WGs x 256thr; wave q owns h in [4q,4q+4); per-lane acc regs
//    {i,f,o,c} for one (b,h) -> no cross-lane in the cell update.
//  - H double-buffered bf16 in ws.
//  - R2: distributed epoch barrier (NO atomic RMW): per-WG arrival flags +
//    go-word, relaxed agent-scope atomic ld/st, one release + one acquire
//    fence per WG per step. Y via per-WG partial buffer + final reduce kernel
//    (removes 2048 atomicAdd RMWs/step from the critical path).

typedef short bf16x8 __attribute__((ext_vector_type(8)));
typedef float f32x4  __attribute__((ext_vector_type(4)));
typedef unsigned short ushort_t;

#define S_LEN 1024
#define NB    64
#define NH    512
#define NE    128
#define NWG   32

// workspace byte offsets
#define OFF_WPACK 0UL                          // 128*20*64*16 = 2,621,440
#define OFF_XBF   2621440UL                    // 1024*64*128*2 = 16,777,216
#define OFF_HBUF  19398656UL                   // 2*64*512*2 = 131,072
#define OFF_V     19529728UL                   // 512*4
#define OFF_C0S   19531776UL                   // 16
#define OFF_FLAGS 19533824UL                   // arrival: 32 words spaced 128B = 4096
#define OFF_GO    (OFF_FLAGS + 4096UL)         // 64
#define OFF_YPART (OFF_FLAGS + 8192UL)         // 1024*32*64*4 = 8,388,608

__device__ __forceinline__ ushort_t f2bf(float f){
    union { float f; unsigned u; } v; v.f = f;
    unsigned u = v.u;
    unsigned r = (u + 0x7fffu + ((u >> 16) & 1u)) >> 16;
    return (ushort_t)r;
}
__device__ __forceinline__ float sigm(float x){ return 1.f / (1.f + __expf(-x)); }
__device__ __forceinline__ float tanh_(float x){ float e = __expf(2.f * x); return (e - 1.f) / (e + 1.f); }

// ---- prep: pack W into MFMA A-operand fragments (bf16) ----------------------
__global__ void pack_weights(const float* __restrict__ Wxi, const float* __restrict__ Whi,
                             const float* __restrict__ Wxf, const float* __restrict__ Whf,
                             const float* __restrict__ Wxo, const float* __restrict__ Who,
                             const float* __restrict__ Wxc, const float* __restrict__ Whc,
                             ushort_t* __restrict__ wpack){
    int bid = blockIdx.x;            // = q*20 + ks
    int q = bid / 20, ks = bid % 20;
    int l = threadIdx.x;             // 0..63
    int m = l & 15, quad = l >> 4;
    int h = q * 4 + (m >> 2), g = m & 3;
    const float* Wh = (g == 0) ? Whi : (g == 1) ? Whf : (g == 2) ? Who : Whc;
    const float* Wx = (g == 0) ? Wxi : (g == 1) ? Wxf : (g == 2) ? Wxo : Wxc;
    union { ushort_t u[8]; uint4 v4; } tmp;
    #pragma unroll
    for (int j = 0; j < 8; j++){
        int k = ks * 32 + quad * 8 + j;
        float w = (k < NH) ? Wh[(size_t)k * NH + h] : Wx[(size_t)(k - NH) * NH + h];
        tmp.u[j] = f2bf(w);
    }
    *(uint4*)(wpack + ((size_t)bid * 64 + l) * 8) = tmp.v4;
}

// ---- prep: bf16 embeddings, layout [s][b][e] --------------------------------
__global__ void prep_x(const int* __restrict__ inputs, const float* __restrict__ emb,
                       ushort_t* __restrict__ xbf){
    unsigned tid = blockIdx.x * 256u + threadIdx.x;   // = (s*64+b)*128 + e
    unsigned e = tid & 127u;
    unsigned b = (tid >> 7) & 63u;
    unsigned s = tid >> 13;
    int row = inputs[(size_t)b * S_LEN + s];
    xbf[tid] = f2bf(emb[(size_t)row * NE + e]);
}

// ---- prep: v = W_hq @ dense_w, c0, flag init, Hbuf[0]=bf16(H0) --------------
__global__ void prep_v(const float* __restrict__ Whq, const float* __restrict__ bq,
                       const float* __restrict__ dw, const float* __restrict__ db,
                       const float* __restrict__ H0, float* __restrict__ v,
                       float* __restrict__ c0, unsigned* __restrict__ flags,
                       unsigned* __restrict__ go, ushort_t* __restrict__ hbuf){
    int h = threadIdx.x;   // 512 threads, 1 block
    float a = 0.f;
    for (int e = 0; e < NE; e++) a += Whq[(size_t)h * NE + e] * dw[e];
    v[h] = a;
    if (h < NWG) flags[h * 32] = 0u;
    if (h == 0){
        float c = db[0];
        for (int e = 0; e < NE; e++) c += bq[e] * dw[e];
        *c0 = c;
        *go = 0u;
    }
    for (int b = 0; b < NB; b++) hbuf[(size_t)b * NH + h] = f2bf(H0[(size_t)b * NH + h]);
}

// ---- final: Y[s,b] = c0 + sum_wg ypart[s][wg][b] -----------------------------
__global__ void reduce_y(const float* __restrict__ ypart, const float* __restrict__ c0,
                         float* __restrict__ dout){
    int t = blockIdx.x * 256 + threadIdx.x;   // t = s*64 + b, 65536 total
    int s = t >> 6, b = t & 63;
    float a = *c0;
    #pragma unroll 4
    for (int w = 0; w < NWG; w++) a += ypart[((size_t)s * NWG + w) * NB + b];
    dout[t] = a;
}

// ---- the recurrence ---------------------------------------------------------
__launch_bounds__(256, 1)
__global__ void lstm_coop(const float* __restrict__ C0,
                          const float* __restrict__ b_i, const float* __restrict__ b_f,
                          const float* __restrict__ b_o, const float* __restrict__ b_c,
                          const ushort_t* __restrict__ wpack, const ushort_t* __restrict__ xbf,
                          ushort_t* __restrict__ hbuf, const float* __restrict__ v,
                          unsigned* __restrict__ flags, unsigned* __restrict__ go,
                          float* __restrict__ ypart, float* __restrict__ dout){
    __shared__ float yred[4][NB];
    const int tid  = threadIdx.x;
    const int lane = tid & 63;
    const int wv   = tid >> 6;
    const int wg   = blockIdx.x;
    const int q    = wg * 4 + wv;           // global wave id, 0..127
    const int quad = lane >> 4;
    const int col  = lane & 15;
    const int h    = q * 4 + quad;          // this lane's h column

    // persistent weights: 20 A-fragments (K=640)
    bf16x8 wfrag[20];
    #pragma unroll
    for (int ks = 0; ks < 20; ks++)
        wfrag[ks] = *(const bf16x8*)(wpack + ((size_t)(q * 20 + ks) * 64 + lane) * 8);

    const float bias0 = b_i[h], bias1 = b_f[h], bias2 = b_o[h], bias3 = b_c[h];
    const float vv = v[h];

    float C[4];
    #pragma unroll
    for (int t = 0; t < 4; t++) C[t] = C0[(size_t)(t * 16 + col) * NH + h];

    for (int s = 0; s < S_LEN; s++){
        const ushort_t* hrd = hbuf + (size_t)(s & 1) * NB * NH;
        ushort_t*       hwr = hbuf + (size_t)((s + 1) & 1) * NB * NH;
        const ushort_t* xrd = xbf + (size_t)s * NB * NE;

        f32x4 acc[4];
        #pragma unroll
        for (int t = 0; t < 4; t++) acc[t] = (f32x4){0.f, 0.f, 0.f, 0.f};

        // K = 0..511 : H part (B-frag: lane holds H[b=16t+col][k .. k+7])
        #pragma unroll
        for (int ks = 0; ks < 16; ks++){
            #pragma unroll
            for (int t = 0; t < 4; t++){
                bf16x8 bfr = *(const bf16x8*)(hrd + (size_t)(t * 16 + col) * NH + ks * 32 + quad * 8);
                acc[t] = __builtin_amdgcn_mfma_f32_16x16x32_bf16(wfrag[ks], bfr, acc[t], 0, 0, 0);
            }
        }
        // K = 512..639 : x part
        #pragma unroll
        for (int ks = 16; ks < 20; ks++){
            #pragma unroll
            for (int t = 0; t < 4; t++){
                bf16x8 bfr = *(const bf16x8*)(xrd + (size_t)(t * 16 + col) * NE + (ks - 16) * 32 + quad * 8);
                acc[t] = __builtin_amdgcn_mfma_f32_16x16x32_bf16(wfrag[ks], bfr, acc[t], 0, 0, 0);
            }
        }

        // cell update: acc[t] regs = {i,f,o,c} gates for batch 16t+col at column h
        #pragma unroll
        for (int t = 0; t < 4; t++){
            const int b = t * 16 + col;
            float I = sigm(acc[t][0] + bias0);
            float F = sigm(acc[t][1] + bias1);
            float O = sigm(acc[t][2] + bias2);
            float G = tanh_(acc[t][3] + bias3);
            float Cn = F * C[t] + I * G;
            float Hn = O * tanh_(Cn);
            C[t] = Cn;
            hwr[(size_t)b * NH + h] = f2bf(Hn);
            float p = Hn * vv;                      // Y partial: sum this wave's 4 h
            p += __shfl_xor(p, 16, 64);
            p += __shfl_xor(p, 32, 64);
            if (quad == 0) yred[wv][b] = p;
            if (s == S_LEN - 1){
                dout[65536 + (size_t)b * NH + h] = Hn;   // final H
                dout[98304 + (size_t)b * NH + h] = Cn;   // final C
            }
        }
        // (A) publishes yred; also drains every wave's H stores (vmcnt(0) before s_barrier)
        __syncthreads();
        if (tid < NB){
            float yy = yred[0][tid] + yred[1][tid] + yred[2][tid] + yred[3][tid];
            ypart[((size_t)s * NWG + wg) * NB + tid] = yy;
        }
        if (s == S_LEN - 1) break;

        // ---- distributed epoch barrier (no RMW) ----
        const unsigned e = (unsigned)(s + 1);
        if (tid == 0){
            __builtin_amdgcn_fence(__ATOMIC_RELEASE, "agent");    // push H to coherence point
            __hip_atomic_store(&flags[wg * 32], e, __ATOMIC_RELAXED, __HIP_MEMORY_SCOPE_AGENT);
        }
        if (wg == 0){
            if (tid < NWG){
                while (__hip_atomic_load(&flags[tid * 32], __ATOMIC_RELAXED,
                                         __HIP_MEMORY_SCOPE_AGENT) < e)
                    __builtin_amdgcn_s_sleep(1);
            }
            // wave-0 reconvergence: all 32 polls done before tid 0 proceeds
            if (tid == 0)
                __hip_atomic_store(go, e, __ATOMIC_RELAXED, __HIP_MEMORY_SCOPE_AGENT);
        }
        if (tid == 0){
            while (__hip_atomic_load(go, __ATOMIC_RELAXED, __HIP_MEMORY_SCOPE_AGENT) < e)
                __builtin_amdgcn_s_sleep(1);
            __builtin_amdgcn_fence(__ATOMIC_ACQUIRE, "agent");    // invalidate CU L1 + XCD L2
        }
        __syncthreads();   // (B)
    }
}

extern "C" void kernel_launch(void* const* d_in, const int* in_sizes, int n_in,
                              void* d_out, int out_size, void* d_ws, size_t ws_size,
                              hipStream_t stream){
    const int*   inputs = (const int*)  d_in[0];
    const float* H0     = (const float*)d_in[1];
    const float* C0     = (const float*)d_in[2];
    const float* emb    = (const float*)d_in[3];
    const float* W_xi   = (const float*)d_in[4];
    const float* W_hi   = (const float*)d_in[5];
    const float* b_i    = (const float*)d_in[6];
    const float* W_xf   = (const float*)d_in[7];
    const float* W_hf   = (const float*)d_in[8];
    const float* b_f    = (const float*)d_in[9];
    const float* W_xo   = (const float*)d_in[10];
    const float* W_ho   = (const float*)d_in[11];
    const float* b_o    = (const float*)d_in[12];
    const float* W_xc   = (const float*)d_in[13];
    const float* W_hc   = (const float*)d_in[14];
    const float* b_c    = (const float*)d_in[15];
    const float* W_hq   = (const float*)d_in[16];
    const float* b_q    = (const float*)d_in[17];
    const float* dw     = (const float*)d_in[18];
    const float* db     = (const float*)d_in[19];
    float* dout = (float*)d_out;

    char* ws = (char*)d_ws;
    ushort_t* wpack = (ushort_t*)(ws + OFF_WPACK);
    ushort_t* xbf   = (ushort_t*)(ws + OFF_XBF);
    ushort_t* hbuf  = (ushort_t*)(ws + OFF_HBUF);
    float*    v     = (float*)   (ws + OFF_V);
    float*    c0    = (float*)   (ws + OFF_C0S);
    unsigned* flags = (unsigned*)(ws + OFF_FLAGS);
    unsigned* go    = (unsigned*)(ws + OFF_GO);
    float*    ypart = (float*)   (ws + OFF_YPART);

    pack_weights<<<dim3(128 * 20), dim3(64), 0, stream>>>(W_xi, W_hi, W_xf, W_hf,
                                                          W_xo, W_ho, W_xc, W_hc, wpack);
    prep_x<<<dim3((S_LEN * NB * NE) / 256), dim3(256), 0, stream>>>(inputs, emb, xbf);
    prep_v<<<dim3(1), dim3(512), 0, stream>>>(W_hq, b_q, dw, db, H0, v, c0, flags, go, hbuf);

    void* args[] = { (void*)&C0, (void*)&b_i, (void*)&b_f, (void*)&b_o, (void*)&b_c,
                     (void*)&wpack, (void*)&xbf, (void*)&hbuf, (void*)&v,
                     (void*)&flags, (void*)&go, (void*)&ypart, (void*)&dout };
    hipLaunchCooperativeKernel((void*)lstm_coop, dim3(NWG), dim3(256), args, 0, stream);

    reduce_y<<<dim3(65536 / 256), dim3(256), 0, stream>>>(ypart, c0, dout);
}

// Round 3
// 6036.349 us; speedup vs baseline: 3.4672x; 3.3295x over previous
//
#include <hip/hip_runtime.h>

// LSTM LM forward on gfx950.
// R3 design:
//  - Output head folded: Y = H·v + c0, v = W_hq@dense_w (exact reassociation).
//  - Batch-parallel split: 4 independent groups of 16 batches; group g = 32 WGs
//    (wg = g*32 + wgin), group-local epoch barrier (fan-in 32, no RMW).
//  - Recurrent GEMM D = W^T·A^T, A=[H|x] (K=640), MFMA 16x16x32 bf16, weights
//    persistent in VGPRs (80/lane = 20 frags), fp32 state/gates.
//  - Per step: WG stages its group's H (16KB) + x (4KB) into LDS with uint4
//    copies (one pipelined LIC latency instead of 40 serialized register-starved
//    global loads -> this was the 17 us/step in R1/R2), then 20 MFMA from
//    ds_read_b128 (+1 uint4 row pad -> 2-way bank conflicts = free).
//  - Wave wv handles h-slot q = wgin*4+wv; lane acc regs = {i,f,o,c} for one
//    (b = g*16+col, h = 4q+quad) -> zero cross-lane in the cell update.

typedef short bf16x8 __attribute__((ext_vector_type(8)));
typedef float f32x4  __attribute__((ext_vector_type(4)));
typedef unsigned short ushort_t;

#define S_LEN 1024
#define NB    64
#define NH    512
#define NE    128
#define NGRP  4
#define NWPG  32              // WGs per group
#define NWGT  (NGRP * NWPG)   // 128 total

// workspace byte offsets
#define OFF_WPACK 0UL                          // 128*20*64*16 = 2,621,440
#define OFF_XBF   2621440UL                    // 1024*64*128*2 = 16,777,216
#define OFF_HBUF  19398656UL                   // 4 grp * 2 buf * 16*512*2 = 131,072
#define OFF_V     19529728UL                   // 512*4
#define OFF_C0S   19531776UL                   // 16
#define OFF_FLAGS 19533824UL                   // 128 words spaced 128B = 16,384
#define OFF_GO    19550208UL                   // 4 words spaced 128B = 512
#define OFF_YPART 19550720UL                   // 1024*128*16*4 = 8,388,608

__device__ __forceinline__ ushort_t f2bf(float f){
    union { float f; unsigned u; } v; v.f = f;
    unsigned u = v.u;
    unsigned r = (u + 0x7fffu + ((u >> 16) & 1u)) >> 16;
    return (ushort_t)r;
}
__device__ __forceinline__ float sigm(float x){ return 1.f / (1.f + __expf(-x)); }
__device__ __forceinline__ float tanh_(float x){ float e = __expf(2.f * x); return (e - 1.f) / (e + 1.f); }

// ---- prep: pack W into MFMA A-operand fragments (bf16) ----------------------
// wpack[q][ks][lane][j]: A[m=lane&15][k=32*ks+(lane>>4)*8+j]; m -> h=4q+(m>>2),
// gate g=m&3; k<512: W_h[g][k][h]; k>=512: W_x[g][k-512][h]
__global__ void pack_weights(const float* __restrict__ Wxi, const float* __restrict__ Whi,
                             const float* __restrict__ Wxf, const float* __restrict__ Whf,
                             const float* __restrict__ Wxo, const float* __restrict__ Who,
                             const float* __restrict__ Wxc, const float* __restrict__ Whc,
                             ushort_t* __restrict__ wpack){
    int bid = blockIdx.x;            // = q*20 + ks
    int q = bid / 20, ks = bid % 20;
    int l = threadIdx.x;             // 0..63
    int m = l & 15, quad = l >> 4;
    int h = q * 4 + (m >> 2), g = m & 3;
    const float* Wh = (g == 0) ? Whi : (g == 1) ? Whf : (g == 2) ? Who : Whc;
    const float* Wx = (g == 0) ? Wxi : (g == 1) ? Wxf : (g == 2) ? Wxo : Wxc;
    union { ushort_t u[8]; uint4 v4; } tmp;
    #pragma unroll
    for (int j = 0; j < 8; j++){
        int k = ks * 32 + quad * 8 + j;
        float w = (k < NH) ? Wh[(size_t)k * NH + h] : Wx[(size_t)(k - NH) * NH + h];
        tmp.u[j] = f2bf(w);
    }
    *(uint4*)(wpack + ((size_t)bid * 64 + l) * 8) = tmp.v4;
}

// ---- prep: bf16 embeddings, layout [s][b][e] --------------------------------
__global__ void prep_x(const int* __restrict__ inputs, const float* __restrict__ emb,
                       ushort_t* __restrict__ xbf){
    unsigned tid = blockIdx.x * 256u + threadIdx.x;   // = (s*64+b)*128 + e
    unsigned e = tid & 127u;
    unsigned b = (tid >> 7) & 63u;
    unsigned s = tid >> 13;
    int row = inputs[(size_t)b * S_LEN + s];
    xbf[tid] = f2bf(emb[(size_t)row * NE + e]);
}

// ---- prep: v = W_hq @ dense_w, c0, flag init, Hbuf[0]=bf16(H0) --------------
__global__ void prep_v(const float* __restrict__ Whq, const float* __restrict__ bq,
                       const float* __restrict__ dw, const float* __restrict__ db,
                       const float* __restrict__ H0, float* __restrict__ v,
                       float* __restrict__ c0, unsigned* __restrict__ flags,
                       unsigned* __restrict__ go, ushort_t* __restrict__ hbuf){
    int h = threadIdx.x;   // 512 threads, 1 block
    float a = 0.f;
    for (int e = 0; e < NE; e++) a += Whq[(size_t)h * NE + e] * dw[e];
    v[h] = a;
    if (h < NWGT) flags[h * 32] = 0u;
    if (h < NGRP) go[h * 32] = 0u;
    if (h == 0){
        float c = db[0];
        for (int e = 0; e < NE; e++) c += bq[e] * dw[e];
        *c0 = c;
    }
    // hbuf layout: [grp][parity][16 b_local][512 h]
    for (int b = 0; b < NB; b++)
        hbuf[(size_t)(b >> 4) * 16384 + (size_t)(b & 15) * NH + h] =
            f2bf(H0[(size_t)b * NH + h]);
}

// ---- final: Y[s,b] = c0 + sum_wgin ypart[s][grp(b)][wgin][b&15] -------------
__global__ void reduce_y(const float* __restrict__ ypart, const float* __restrict__ c0,
                         float* __restrict__ dout){
    int t = blockIdx.x * 256 + threadIdx.x;   // t = s*64 + b, 65536 total
    int s = t >> 6, b = t & 63;
    int g = b >> 4, bl = b & 15;
    float a = *c0;
    const float* base = ypart + (((size_t)s * NGRP + g) * NWPG) * 16 + bl;
    #pragma unroll 4
    for (int w = 0; w < NWPG; w++) a += base[w * 16];
    dout[t] = a;
}

// ---- the recurrence ---------------------------------------------------------
__launch_bounds__(256, 1)
__global__ void lstm_coop(const float* __restrict__ C0,
                          const float* __restrict__ b_i, const float* __restrict__ b_f,
                          const float* __restrict__ b_o, const float* __restrict__ b_c,
                          const ushort_t* __restrict__ wpack, const ushort_t* __restrict__ xbf,
                          ushort_t* __restrict__ hbuf, const float* __restrict__ v,
                          unsigned* __restrict__ flags, unsigned* __restrict__ go,
                          float* __restrict__ ypart, float* __restrict__ dout){
    // LDS: H tile [16 rows][65 uint4] (row = b_local, 520 bf16, +1 uint4 pad),
    //      x tile [16 rows][17 uint4] (136 bf16), y reduction [4][16]
    __shared__ uint4 Hs[16][65];
    __shared__ uint4 Xs[16][17];
    __shared__ float yred[4][16];

    const int tid  = threadIdx.x;
    const int lane = tid & 63;
    const int wv   = tid >> 6;
    const int wg   = blockIdx.x;
    const int g    = wg >> 5;              // batch group 0..3
    const int wgin = wg & 31;              // WG index within group
    const int q    = wgin * 4 + wv;        // h-slot 0..127
    const int quad = lane >> 4;
    const int col  = lane & 15;
    const int h    = q * 4 + quad;         // this lane's h column
    const int b    = g * 16 + col;         // this lane's batch

    // persistent weights: 20 A-fragments (K=640)
    bf16x8 wfrag[20];
    #pragma unroll
    for (int ks = 0; ks < 20; ks++)
        wfrag[ks] = *(const bf16x8*)(wpack + ((size_t)(q * 20 + ks) * 64 + lane) * 8);

    const float bias0 = b_i[h], bias1 = b_f[h], bias2 = b_o[h], bias3 = b_c[h];
    const float vv = v[h];
    float C = C0[(size_t)b * NH + h];

    ushort_t* hgrp = hbuf + (size_t)g * 16384;   // this group's double buffer
    unsigned* myflag = flags + wg * 32;
    unsigned* mygo   = go + g * 32;

    const char* HsB = (const char*)Hs;
    const char* XsB = (const char*)Xs;

    for (int s = 0; s < S_LEN; s++){
        const uint4* hrd4 = (const uint4*)(hgrp + (size_t)(s & 1) * 8192);
        ushort_t*    hwr  = hgrp + (size_t)((s + 1) & 1) * 8192;
        const uint4* xrd4 = (const uint4*)(xbf + ((size_t)s * NB + g * 16) * NE);

        // ---- stage H (1024 uint4) + x (256 uint4) into LDS --------------------
        {
            uint4 t0 = hrd4[tid];
            uint4 t1 = hrd4[tid + 256];
            uint4 t2 = hrd4[tid + 512];
            uint4 t3 = hrd4[tid + 768];
            uint4 tx = xrd4[tid];
            Hs[tid >> 6][tid & 63]                 = t0;
            Hs[(tid + 256) >> 6][(tid + 256) & 63] = t1;
            Hs[(tid + 512) >> 6][(tid + 512) & 63] = t2;
            Hs[(tid + 768) >> 6][(tid + 768) & 63] = t3;
            Xs[tid >> 4][tid & 15]                 = tx;
        }
        __syncthreads();   // S1

        // ---- 20 MFMA from LDS -------------------------------------------------
        f32x4 acc = (f32x4){0.f, 0.f, 0.f, 0.f};
        #pragma unroll
        for (int ks = 0; ks < 16; ks++){
            bf16x8 bfr = *(const bf16x8*)(HsB + col * 1040 + ks * 64 + quad * 16);
            acc = __builtin_amdgcn_mfma_f32_16x16x32_bf16(wfrag[ks], bfr, acc, 0, 0, 0);
        }
        #pragma unroll
        for (int kx = 0; kx < 4; kx++){
            bf16x8 bfr = *(const bf16x8*)(XsB + col * 272 + kx * 64 + quad * 16);
            acc = __builtin_amdgcn_mfma_f32_16x16x32_bf16(wfrag[16 + kx], bfr, acc, 0, 0, 0);
        }

        // ---- cell update: acc regs = {i,f,o,c} for (b, h) ---------------------
        float I = sigm(acc[0] + bias0);
        float F = sigm(acc[1] + bias1);
        float O = sigm(acc[2] + bias2);
        float G = tanh_(acc[3] + bias3);
        float Cn = F * C + I * G;
        float Hn = O * tanh_(Cn);
        C = Cn;
        hwr[(size_t)col * NH + h] = f2bf(Hn);
        float p = Hn * vv;                        // Y partial: sum this wave's 4 h
        p += __shfl_xor(p, 16, 64);
        p += __shfl_xor(p, 32, 64);
        if (quad == 0) yred[wv][col] = p;
        if (s == S_LEN - 1){
            dout[65536 + (size_t)b * NH + h] = Hn;   // final H
            dout[98304 + (size_t)b * NH + h] = Cn;   // final C
        }
        // S2: publishes yred; __syncthreads drains every wave's H stores (vmcnt(0))
        __syncthreads();
        if (tid < 16)
            ypart[(((size_t)s * NGRP + g) * NWPG + wgin) * 16 + tid] =
                yred[0][tid] + yred[1][tid] + yred[2][tid] + yred[3][tid];
        if (s == S_LEN - 1) break;

        // ---- group-local epoch barrier (no RMW) -------------------------------
        const unsigned e = (unsigned)(s + 1);
        if (tid == 0){
            __builtin_amdgcn_fence(__ATOMIC_RELEASE, "agent");    // wbl2: push H to LIC
            __hip_atomic_store(myflag, e, __ATOMIC_RELAXED, __HIP_MEMORY_SCOPE_AGENT);
        }
        if (wgin == 0 && tid < NWPG){
            while (__hip_atomic_load(&flags[(g * 32 + tid) * 32], __ATOMIC_RELAXED,
                                     __HIP_MEMORY_SCOPE_AGENT) < e)
                __builtin_amdgcn_s_sleep(1);
        }
        if (wgin == 0 && tid == 0)
            __hip_atomic_store(mygo, e, __ATOMIC_RELAXED, __HIP_MEMORY_SCOPE_AGENT);
        if (tid == 0){
            while (__hip_atomic_load(mygo, __ATOMIC_RELAXED, __HIP_MEMORY_SCOPE_AGENT) < e)
                __builtin_amdgcn_s_sleep(1);
            __builtin_amdgcn_fence(__ATOMIC_ACQUIRE, "agent");    // inv L1+L2
        }
        __syncthreads();   // S3
    }
}

extern "C" void kernel_launch(void* const* d_in, const int* in_sizes, int n_in,
                              void* d_out, int out_size, void* d_ws, size_t ws_size,
                              hipStream_t stream){
    const int*   inputs = (const int*)  d_in[0];
    const float* H0     = (const float*)d_in[1];
    const float* C0     = (const float*)d_in[2];
    const float* emb    = (const float*)d_in[3];
    const float* W_xi   = (const float*)d_in[4];
    const float* W_hi   = (const float*)d_in[5];
    const float* b_i    = (const float*)d_in[6];
    const float* W_xf   = (const float*)d_in[7];
    const float* W_hf   = (const float*)d_in[8];
    const float* b_f    = (const float*)d_in[9];
    const float* W_xo   = (const float*)d_in[10];
    const float* W_ho   = (const float*)d_in[11];
    const float* b_o    = (const float*)d_in[12];
    const float* W_xc   = (const float*)d_in[13];
    const float* W_hc   = (const float*)d_in[14];
    const float* b_c    = (const float*)d_in[15];
    const float* W_hq   = (const float*)d_in[16];
    const float* b_q    = (const float*)d_in[17];
    const float* dw     = (const float*)d_in[18];
    const float* db     = (const float*)d_in[19];
    float* dout = (float*)d_out;

    char* ws = (char*)d_ws;
    ushort_t* wpack = (ushort_t*)(ws + OFF_WPACK);
    ushort_t* xbf   = (ushort_t*)(ws + OFF_XBF);
    ushort_t* hbuf  = (ushort_t*)(ws + OFF_HBUF);
    float*    v     = (float*)   (ws + OFF_V);
    float*    c0    = (float*)   (ws + OFF_C0S);
    unsigned* flags = (unsigned*)(ws + OFF_FLAGS);
    unsigned* go    = (unsigned*)(ws + OFF_GO);
    float*    ypart = (float*)   (ws + OFF_YPART);

    pack_weights<<<dim3(128 * 20), dim3(64), 0, stream>>>(W_xi, W_hi, W_xf, W_hf,
                                                          W_xo, W_ho, W_xc, W_hc, wpack);
    prep_x<<<dim3((S_LEN * NB * NE) / 256), dim3(256), 0, stream>>>(inputs, emb, xbf);
    prep_v<<<dim3(1), dim3(512), 0, stream>>>(W_hq, b_q, dw, db, H0, v, c0, flags, go, hbuf);

    void* args[] = { (void*)&C0, (void*)&b_i, (void*)&b_f, (void*)&b_o, (void*)&b_c,
                     (void*)&wpack, (void*)&xbf, (void*)&hbuf, (void*)&v,
                     (void*)&flags, (void*)&go, (void*)&ypart, (void*)&dout };
    hipLaunchCooperativeKernel((void*)lstm_coop, dim3(NWGT), dim3(256), args, 0, stream);

    reduce_y<<<dim3(65536 / 256), dim3(256), 0, stream>>>(ypart, c0, dout);
}

// Round 4
// 4288.381 us; speedup vs baseline: 4.8805x; 1.4076x over previous
//
#include <hip/hip_runtime.h>

// LSTM LM forward on gfx950.
// R4 design (delta vs R3):
//  - Fence-free H exchange: H written as relaxed AGENT-scope atomic dword
//    stores (write-through to LIC, lane-pairs pack 2 bf16 via shfl_xor(16));
//    H staged back via relaxed AGENT-scope atomic dword loads (bypass L1/L2,
//    always fresh) -> the per-step acquire/inv fence is GONE, so x tiles and
//    other read-only data stay L2-resident. Release fence remains (cheap: no
//    dirty H lines in L2 anymore).
//  - Single-RTT barrier: no go-word; every WG's wave 0 polls all 32 peer
//    flags directly.
//  - x tile double-buffered in LDS, prefetched during the poll phase.
// Carried from R3: 4 independent batch groups x 32 WGs, weights persistent in
// VGPRs (20 A-frags), MFMA 16x16x32 bf16, lane acc = {i,f,o,c} for one (b,h),
// folded output head Y = H.v + c0.

typedef short bf16x8 __attribute__((ext_vector_type(8)));
typedef float f32x4  __attribute__((ext_vector_type(4)));
typedef unsigned short ushort_t;

#define S_LEN 1024
#define NB    64
#define NH    512
#define NE    128
#define NGRP  4
#define NWPG  32              // WGs per group
#define NWGT  (NGRP * NWPG)   // 128 total

// workspace byte offsets
#define OFF_WPACK 0UL                          // 128*20*64*16 = 2,621,440
#define OFF_XBF   2621440UL                    // 1024*64*128*2 = 16,777,216
#define OFF_HBUF  19398656UL                   // 4 grp * 2 buf * 16*512*2 = 131,072
#define OFF_V     19529728UL                   // 512*4
#define OFF_C0S   19531776UL                   // 16
#define OFF_FLAGS 19533824UL                   // 128 words spaced 128B = 16,384
#define OFF_YPART 19550720UL                   // 1024*128*16*4 = 8,388,608

__device__ __forceinline__ ushort_t f2bf(float f){
    union { float f; unsigned u; } v; v.f = f;
    unsigned u = v.u;
    unsigned r = (u + 0x7fffu + ((u >> 16) & 1u)) >> 16;
    return (ushort_t)r;
}
__device__ __forceinline__ float sigm(float x){ return 1.f / (1.f + __expf(-x)); }
__device__ __forceinline__ float tanh_(float x){ float e = __expf(2.f * x); return (e - 1.f) / (e + 1.f); }

// ---- prep: pack W into MFMA A-operand fragments (bf16) ----------------------
// wpack[q][ks][lane][j]: A[m=lane&15][k=32*ks+(lane>>4)*8+j]; m -> h=4q+(m>>2),
// gate g=m&3; k<512: W_h[g][k][h]; k>=512: W_x[g][k-512][h]
__global__ void pack_weights(const float* __restrict__ Wxi, const float* __restrict__ Whi,
                             const float* __restrict__ Wxf, const float* __restrict__ Whf,
                             const float* __restrict__ Wxo, const float* __restrict__ Who,
                             const float* __restrict__ Wxc, const float* __restrict__ Whc,
                             ushort_t* __restrict__ wpack){
    int bid = blockIdx.x;            // = q*20 + ks
    int q = bid / 20, ks = bid % 20;
    int l = threadIdx.x;             // 0..63
    int m = l & 15, quad = l >> 4;
    int h = q * 4 + (m >> 2), g = m & 3;
    const float* Wh = (g == 0) ? Whi : (g == 1) ? Whf : (g == 2) ? Who : Whc;
    const float* Wx = (g == 0) ? Wxi : (g == 1) ? Wxf : (g == 2) ? Wxo : Wxc;
    union { ushort_t u[8]; uint4 v4; } tmp;
    #pragma unroll
    for (int j = 0; j < 8; j++){
        int k = ks * 32 + quad * 8 + j;
        float w = (k < NH) ? Wh[(size_t)k * NH + h] : Wx[(size_t)(k - NH) * NH + h];
        tmp.u[j] = f2bf(w);
    }
    *(uint4*)(wpack + ((size_t)bid * 64 + l) * 8) = tmp.v4;
}

// ---- prep: bf16 embeddings, layout [s][b][e] --------------------------------
__global__ void prep_x(const int* __restrict__ inputs, const float* __restrict__ emb,
                       ushort_t* __restrict__ xbf){
    unsigned tid = blockIdx.x * 256u + threadIdx.x;   // = (s*64+b)*128 + e
    unsigned e = tid & 127u;
    unsigned b = (tid >> 7) & 63u;
    unsigned s = tid >> 13;
    int row = inputs[(size_t)b * S_LEN + s];
    xbf[tid] = f2bf(emb[(size_t)row * NE + e]);
}

// ---- prep: v = W_hq @ dense_w, c0, flag init, Hbuf[0]=bf16(H0) --------------
__global__ void prep_v(const float* __restrict__ Whq, const float* __restrict__ bq,
                       const float* __restrict__ dw, const float* __restrict__ db,
                       const float* __restrict__ H0, float* __restrict__ v,
                       float* __restrict__ c0, unsigned* __restrict__ flags,
                       ushort_t* __restrict__ hbuf){
    int h = threadIdx.x;   // 512 threads, 1 block
    float a = 0.f;
    for (int e = 0; e < NE; e++) a += Whq[(size_t)h * NE + e] * dw[e];
    v[h] = a;
    if (h < NWGT) flags[h * 32] = 0u;
    if (h == 0){
        float c = db[0];
        for (int e = 0; e < NE; e++) c += bq[e] * dw[e];
        *c0 = c;
    }
    // hbuf layout: [grp][parity][16 b_local][512 h]
    for (int b = 0; b < NB; b++)
        hbuf[(size_t)(b >> 4) * 16384 + (size_t)(b & 15) * NH + h] =
            f2bf(H0[(size_t)b * NH + h]);
}

// ---- final: Y[s,b] = c0 + sum_wgin ypart[s][grp(b)][wgin][b&15] -------------
__global__ void reduce_y(const float* __restrict__ ypart, const float* __restrict__ c0,
                         float* __restrict__ dout){
    int t = blockIdx.x * 256 + threadIdx.x;   // t = s*64 + b, 65536 total
    int s = t >> 6, b = t & 63;
    int g = b >> 4, bl = b & 15;
    float a = *c0;
    const float* base = ypart + (((size_t)s * NGRP + g) * NWPG) * 16 + bl;
    #pragma unroll 4
    for (int w = 0; w < NWPG; w++) a += base[w * 16];
    dout[t] = a;
}

// ---- the recurrence ---------------------------------------------------------
__launch_bounds__(256, 1)
__global__ void lstm_coop(const float* __restrict__ C0,
                          const float* __restrict__ b_i, const float* __restrict__ b_f,
                          const float* __restrict__ b_o, const float* __restrict__ b_c,
                          const ushort_t* __restrict__ wpack, const ushort_t* __restrict__ xbf,
                          ushort_t* __restrict__ hbuf, const float* __restrict__ v,
                          unsigned* __restrict__ flags,
                          float* __restrict__ ypart, float* __restrict__ dout){
    // LDS: H tile [16 rows][65 uint4] (row = b_local, +1 uint4 pad -> dword
    // stride 260, conflict-free b32 staging writes), x tile double-buffered
    // [2][16][17] uint4, y reduction [4][16]
    __shared__ uint4 Hs[16][65];
    __shared__ uint4 Xs[2][16][17];
    __shared__ float yred[4][16];

    const int tid  = threadIdx.x;
    const int lane = tid & 63;
    const int wv   = tid >> 6;
    const int wg   = blockIdx.x;
    const int g    = wg >> 5;              // batch group 0..3
    const int wgin = wg & 31;              // WG index within group
    const int q    = wgin * 4 + wv;        // h-slot 0..127
    const int quad = lane >> 4;
    const int col  = lane & 15;
    const int h    = q * 4 + quad;         // this lane's h column
    const int b    = g * 16 + col;         // this lane's batch

    // persistent weights: 20 A-fragments (K=640)
    bf16x8 wfrag[20];
    #pragma unroll
    for (int ks = 0; ks < 20; ks++)
        wfrag[ks] = *(const bf16x8*)(wpack + ((size_t)(q * 20 + ks) * 64 + lane) * 8);

    const float bias0 = b_i[h], bias1 = b_f[h], bias2 = b_o[h], bias3 = b_c[h];
    const float vv = v[h];
    float C = C0[(size_t)b * NH + h];

    ushort_t* hgrp = hbuf + (size_t)g * 16384;   // this group's double buffer
    unsigned* myflag = flags + wg * 32;

    const char* HsB = (const char*)Hs;
    const char* XsB = (const char*)Xs;
    unsigned* HsD = (unsigned*)Hs;

    // preload x tile for s=0 into Xs[0]
    {
        const uint4* x0 = (const uint4*)(xbf + (size_t)(g * 16) * NE);
        Xs[0][tid >> 4][tid & 15] = x0[tid];
    }

    for (int s = 0; s < S_LEN; s++){
        // ---- stage H via AGENT-scope dword loads (LIC-direct, always fresh) ---
        {
            unsigned* hrd_u = (unsigned*)(hgrp + (size_t)(s & 1) * 8192);
            unsigned hv[16];
            #pragma unroll
            for (int j = 0; j < 16; j++)
                hv[j] = __hip_atomic_load(hrd_u + j * 256 + tid, __ATOMIC_RELAXED,
                                          __HIP_MEMORY_SCOPE_AGENT);
            #pragma unroll
            for (int j = 0; j < 16; j++)
                HsD[j * 260 + tid] = hv[j];      // b_local=j, dword tid: conflict-free
        }
        __syncthreads();   // S1: Hs + Xs[s&1] ready

        // ---- 20 MFMA from LDS -------------------------------------------------
        f32x4 acc = (f32x4){0.f, 0.f, 0.f, 0.f};
        #pragma unroll
        for (int ks = 0; ks < 16; ks++){
            bf16x8 bfr = *(const bf16x8*)(HsB + col * 1040 + ks * 64 + quad * 16);
            acc = __builtin_amdgcn_mfma_f32_16x16x32_bf16(wfrag[ks], bfr, acc, 0, 0, 0);
        }
        #pragma unroll
        for (int kx = 0; kx < 4; kx++){
            bf16x8 bfr = *(const bf16x8*)(XsB + (s & 1) * 4352 + col * 272 + kx * 64 + quad * 16);
            acc = __builtin_amdgcn_mfma_f32_16x16x32_bf16(wfrag[16 + kx], bfr, acc, 0, 0, 0);
        }

        // ---- cell update: acc regs = {i,f,o,c} for (b, h) ---------------------
        float I = sigm(acc[0] + bias0);
        float F = sigm(acc[1] + bias1);
        float O = sigm(acc[2] + bias2);
        float G = tanh_(acc[3] + bias3);
        float Cn = F * C + I * G;
        float Hn = O * tanh_(Cn);
        C = Cn;

        // pack lane-pair (quad, quad^1) -> one dword, AGENT store (write-through)
        {
            float Hn_hi = __shfl_xor(Hn, 16, 64);     // partner quad's value
            unsigned hp = (unsigned)f2bf(Hn) | ((unsigned)f2bf(Hn_hi) << 16);
            if ((quad & 1) == 0){
                unsigned* hwr_u = (unsigned*)(hgrp + (size_t)((s + 1) & 1) * 8192);
                unsigned idx = (unsigned)col * 256 + (unsigned)(q * 2) + (unsigned)(quad >> 1);
                __hip_atomic_store(hwr_u + idx, hp, __ATOMIC_RELAXED,
                                   __HIP_MEMORY_SCOPE_AGENT);
            }
        }

        float p = Hn * vv;                        // Y partial: sum this wave's 4 h
        p += __shfl_xor(p, 16, 64);
        p += __shfl_xor(p, 32, 64);
        if (quad == 0) yred[wv][col] = p;
        if (s == S_LEN - 1){
            dout[65536 + (size_t)b * NH + h] = Hn;   // final H
            dout[98304 + (size_t)b * NH + h] = Cn;   // final C
        }
        // S2: publishes yred; each wave drains its H stores (vmcnt(0)) at barrier
        __syncthreads();
        if (tid < 16)
            ypart[(((size_t)s * NGRP + g) * NWPG + wgin) * 16 + tid] =
                yred[0][tid] + yred[1][tid] + yred[2][tid] + yred[3][tid];
        if (s == S_LEN - 1) break;

        // ---- flag publish (single-RTT barrier, no go-phase) -------------------
        const unsigned e = (unsigned)(s + 1);
        if (tid == 0){
            __builtin_amdgcn_fence(__ATOMIC_RELEASE, "agent");  // drain XCD write path
            __hip_atomic_store(myflag, e, __ATOMIC_RELAXED, __HIP_MEMORY_SCOPE_AGENT);
        }
        // x prefetch for s+1 overlaps the poll
        {
            const uint4* xn = (const uint4*)(xbf + ((size_t)(s + 1) * NB + g * 16) * NE);
            Xs[(s + 1) & 1][tid >> 4][tid & 15] = xn[tid];
        }
        if (tid < NWPG){
            unsigned* fp = flags + (g * NWPG + tid) * 32;
            while (__hip_atomic_load(fp, __ATOMIC_RELAXED, __HIP_MEMORY_SCOPE_AGENT) < e)
                __builtin_amdgcn_s_sleep(1);
        }
        __syncthreads();   // S3
    }
}

extern "C" void kernel_launch(void* const* d_in, const int* in_sizes, int n_in,
                              void* d_out, int out_size, void* d_ws, size_t ws_size,
                              hipStream_t stream){
    const int*   inputs = (const int*)  d_in[0];
    const float* H0     = (const float*)d_in[1];
    const float* C0     = (const float*)d_in[2];
    const float* emb    = (const float*)d_in[3];
    const float* W_xi   = (const float*)d_in[4];
    const float* W_hi   = (const float*)d_in[5];
    const float* b_i    = (const float*)d_in[6];
    const float* W_xf   = (const float*)d_in[7];
    const float* W_hf   = (const float*)d_in[8];
    const float* b_f    = (const float*)d_in[9];
    const float* W_xo   = (const float*)d_in[10];
    const float* W_ho   = (const float*)d_in[11];
    const float* b_o    = (const float*)d_in[12];
    const float* W_xc   = (const float*)d_in[13];
    const float* W_hc   = (const float*)d_in[14];
    const float* b_c    = (const float*)d_in[15];
    const float* W_hq   = (const float*)d_in[16];
    const float* b_q    = (const float*)d_in[17];
    const float* dw     = (const float*)d_in[18];
    const float* db     = (const float*)d_in[19];
    float* dout = (float*)d_out;

    char* ws = (char*)d_ws;
    ushort_t* wpack = (ushort_t*)(ws + OFF_WPACK);
    ushort_t* xbf   = (ushort_t*)(ws + OFF_XBF);
    ushort_t* hbuf  = (ushort_t*)(ws + OFF_HBUF);
    float*    v     = (float*)   (ws + OFF_V);
    float*    c0    = (float*)   (ws + OFF_C0S);
    unsigned* flags = (unsigned*)(ws + OFF_FLAGS);
    float*    ypart = (float*)   (ws + OFF_YPART);

    pack_weights<<<dim3(128 * 20), dim3(64), 0, stream>>>(W_xi, W_hi, W_xf, W_hf,
                                                          W_xo, W_ho, W_xc, W_hc, wpack);
    prep_x<<<dim3((S_LEN * NB * NE) / 256), dim3(256), 0, stream>>>(inputs, emb, xbf);
    prep_v<<<dim3(1), dim3(512), 0, stream>>>(W_hq, b_q, dw, db, H0, v, c0, flags, hbuf);

    void* args[] = { (void*)&C0, (void*)&b_i, (void*)&b_f, (void*)&b_o, (void*)&b_c,
                     (void*)&wpack, (void*)&xbf, (void*)&hbuf, (void*)&v,
                     (void*)&flags, (void*)&ypart, (void*)&dout };
    hipLaunchCooperativeKernel((void*)lstm_coop, dim3(NWGT), dim3(256), args, 0, stream);

    reduce_y<<<dim3(65536 / 256), dim3(256), 0, stream>>>(ypart, c0, dout);
}